// Round 13
// baseline (99.323 us; speedup 1.0000x reference)
//
#include <hip/hip_runtime.h>

constexpr int Fdim = 2000;
constexpr int Wdim = 4000;
constexpr int Edim = 16;
constexpr int Hdim = 64;
constexpr int Bdim = 256;
constexpr float kLog2e = 1.4426950408889634f;

// ---- MFMA-path padded dims
constexpr int Mp = 2048;        // padded F
constexpr int Np = 4096;        // padded W
constexpr int Kp = 320;         // 5 tanh powers x 64 h
constexpr int NCHUNK = Np / 64; // 64 w-chunks of partials

typedef _Float16 f16x8 __attribute__((ext_vector_type(8)));
typedef _Float16 f16x2 __attribute__((ext_vector_type(2)));
typedef float f32x4 __attribute__((ext_vector_type(4)));

__device__ __forceinline__ float fast_exp2(float x) {
#if __has_builtin(__builtin_amdgcn_exp2f)
  return __builtin_amdgcn_exp2f(x);
#else
  return exp2f(x);
#endif
}
__device__ __forceinline__ float fast_rcp(float x) {
#if __has_builtin(__builtin_amdgcn_rcpf)
  return __builtin_amdgcn_rcpf(x);
#else
  return 1.0f / x;
#endif
}
__device__ __forceinline__ float dev_tanh(float x) {
  return 1.0f - 2.0f * fast_rcp(fast_exp2(2.0f * kLog2e * x) + 1.0f);
}
__device__ __forceinline__ f16x2 pack_f16(float a, float b) {
  return __builtin_bit_cast(f16x2, __builtin_amdgcn_cvt_pkrtz(a, b));
}

// ---- DPP wave-64 sum (VALU pipe). Result valid in lane 63.
template <int CTRL>
__device__ __forceinline__ float dpp_part(float x) {
  return __int_as_float(
      __builtin_amdgcn_update_dpp(0, __float_as_int(x), CTRL, 0xF, 0xF, true));
}
__device__ __forceinline__ float wave64_sum(float x) {
  const float x0 = x;
  x += dpp_part<0x111>(x0);
  x += dpp_part<0x112>(x0);
  x += dpp_part<0x113>(x0);
  x += dpp_part<0x114>(x);
  x += dpp_part<0x118>(x);
  x += dpp_part<0x142>(x);
  x += dpp_part<0x143>(x);
  return x;
}

// prep2: fp16 GEMM operands + hemb B-fragments + fused mask-layout detect.
//   A[f][j*64+h] = tanh(s)^j (j=0..4), s = femb@Ww[:E]; rows >=Fdim zeroed
//   B[w][j*64+h] = Wu[h]*{q,1-q^2,q^3-q,q^2-q^4,-q^3}, q=tanh(hid+b); pad 0
//   hembB[widx][lane][i] = hemb[widx*32+(lane>>4)*8+i][lane&15]  (fp16 frags)
//   mflag = 1 if mask is 1-byte bool layout, 0 if int32.
__global__ __launch_bounds__(256) void prep2_kernel(
    const float* __restrict__ femb, const float* __restrict__ hemb,
    const float* __restrict__ Ww, const float* __restrict__ bw,
    const float* __restrict__ Wu, const unsigned char* __restrict__ mask,
    _Float16* __restrict__ A, _Float16* __restrict__ B,
    _Float16* __restrict__ hembB, int* __restrict__ mflag) {
  constexpr int PA = Fdim * Hdim;                  // 128000 A main
  constexpr int PAZ = PA + (Mp - Fdim) * Kp / 2;   // +7680 A pad (u32)
  constexpr int PB = PAZ + Wdim * Hdim;            // +256000 B main
  constexpr int PBZ = PB + (Np - Wdim) * Kp / 2;   // +15360 B pad (u32)
  constexpr int PH = PBZ + (Np / 32) * 64;         // +8192 hembB
  constexpr int PD = PH + 64;                      // +64 detect wave
  int idx = blockIdx.x * 256 + threadIdx.x;
  if (idx < PA) {
    int f = idx >> 6, h = idx & 63;
    float s = 0.f;
#pragma unroll
    for (int e = 0; e < Edim; ++e)
      s = fmaf(femb[f * Edim + e], Ww[e * Hdim + h], s);
    float p = dev_tanh(s);
    _Float16* a = A + (size_t)f * Kp + h;
    float pj = 1.0f;
#pragma unroll
    for (int j = 0; j < 5; ++j) {
      a[j * 64] = (_Float16)pj;
      pj *= p;
    }
  } else if (idx < PAZ) {
    ((unsigned int*)(A + (size_t)Fdim * Kp))[idx - PA] = 0u;
  } else if (idx < PB) {
    int jj = idx - PAZ;
    int w = jj >> 6, h = jj & 63;
    float t = bw[h];
#pragma unroll
    for (int e = 0; e < Edim; ++e)
      t = fmaf(hemb[w * Edim + e], Ww[(Edim + e) * Hdim + h], t);
    float q = dev_tanh(t);
    float wu = Wu[h];
    float q2 = q * q, q3 = q2 * q;
    _Float16* b = B + (size_t)w * Kp + h;
    b[0 * 64] = (_Float16)(wu * q);
    b[1 * 64] = (_Float16)(wu * (1.0f - q2));
    b[2 * 64] = (_Float16)(wu * (q3 - q));
    b[3 * 64] = (_Float16)(wu * (q2 - q2 * q2));
    b[4 * 64] = (_Float16)(-wu * q3);
  } else if (idx < PBZ) {
    ((unsigned int*)(B + (size_t)Wdim * Kp))[idx - PB] = 0u;
  } else if (idx < PH) {
    int j = idx - PBZ;
    int lane = j & 63;
    int e = lane & 15;
    int wb = (j >> 6) * 32 + (lane >> 4) * 8;
    f16x8 v;
#pragma unroll
    for (int i = 0; i < 8; ++i) {
      int w = wb + i;
      v[i] = (w < Wdim) ? (_Float16)hemb[(size_t)w * Edim + e] : (_Float16)0.f;
    }
    *(f16x8*)(hembB + (size_t)j * 8) = v;
  } else if (idx < PD) {
    // mask layout detect: bytes at i%4!=0 all zero <=> int32 layout
    int l = idx - PH;
    int acc = 0;
    for (int i = l; i < 8192; i += 64)
      if ((i & 3) != 0) acc |= mask[i];
    unsigned long long bl = __ballot(acc != 0);
    if (l == 0) *mflag = (bl != 0ull) ? 1 : 0;
  }
}

// score_ctx: fused, 16f x 64w per wave (8 waves/SIMD), XCD-swizzled.
// First GEMM SWAPPED: mfma(B_w, A_f) -> D col=f (lane&15), row=w.
// Mask + hembB prefetched BEFORE the K-loop (latency hides under MFMA).
// Epilogue: exp2*mask -> fp16 -> per-wave XOR-swizzled LDS tile [16f][64w].
// Second GEMM contracts w -> num[16f][16e]; den via in-reg sum + shfl_xor.
__global__ __launch_bounds__(256, 8) void score_ctx_kernel(
    const _Float16* __restrict__ A, const _Float16* __restrict__ B,
    const unsigned char* __restrict__ mask_b, const int* __restrict__ mflag,
    const _Float16* __restrict__ hembB,
    float* __restrict__ part_num, float* __restrict__ part_den) {
  __shared__ __align__(16) char smem[8192];  // 2 KB per wave
  const int tid = threadIdx.x;
  const int wid = tid >> 6, lane = tid & 63;
  const int wr = wid >> 1, wc = wid & 1;

  // ---- bijective XCD swizzle (2048 blocks, 8 XCDs): XCD c gets 4
  // consecutive w-tiles x all 64 f-tiles -> per-XCD L2 set ~1.6 MB.
  const int lin = blockIdx.y * 32 + blockIdx.x;   // grid (32, 64)
  const int nl = (lin & 7) * 256 + (lin >> 3);
  const int bx = nl >> 6;   // w-tile (128 w) index [0,32)
  const int by = nl & 63;   // f-tile (32 f) index [0,64)

  const int fbase = by * 32 + wr * 16;
  const int wbase = bx * 128 + wc * 64;
  const int lrow = lane & 15, g = lane >> 4;

  // ---- EARLY issue: mask (byte-layout fast path) + hembB fragments
  const int mbyte = *mflag;  // uniform s_load
  const int f_m = fbase + lrow;
  const bool fok = (f_m < Fdim);
  unsigned int mdm[4];
  if (mbyte) {
#pragma unroll
    for (int mw = 0; mw < 4; ++mw) {
      const int w0 = wbase + mw * 16 + g * 4;
      mdm[mw] = (fok && w0 < Wdim)
                    ? *(const unsigned int*)(mask_b + (size_t)f_m * Wdim + w0)
                    : 0u;
    }
  }
  const f16x8 hb0 =
      *(const f16x8*)(hembB + ((size_t)(wbase >> 5) + 0) * 512 + lane * 8);
  const f16x8 hb1 =
      *(const f16x8*)(hembB + ((size_t)(wbase >> 5) + 1) * 512 + lane * 8);

  // ---- first GEMM: accT[mw] = sc^T frags (col=f, row=w)
  f32x4 accT[4];
#pragma unroll
  for (int mw = 0; mw < 4; ++mw) accT[mw] = (f32x4){0.f, 0.f, 0.f, 0.f};

  const _Float16* Bw = B + (size_t)(wbase + lrow) * Kp + g * 8;
  const _Float16* Af = A + (size_t)(fbase + lrow) * Kp + g * 8;
#pragma unroll 2
  for (int ks = 0; ks < Kp / 32; ++ks) {
    f16x8 bw[4];
#pragma unroll
    for (int mw = 0; mw < 4; ++mw)
      bw[mw] = *(const f16x8*)(Bw + (size_t)mw * 16 * Kp + ks * 32);
    const f16x8 af = *(const f16x8*)(Af + ks * 32);
#pragma unroll
    for (int mw = 0; mw < 4; ++mw)
      accT[mw] =
          __builtin_amdgcn_mfma_f32_16x16x32_f16(bw[mw], af, accT[mw], 0, 0, 0);
  }

  // ---- epilogue: exp2 * mask -> fp16 -> swizzled LDS; den partial
  const int* mask_i = (const int*)mask_b;
  char* sbase = smem + wid * 2048;
  const int sw = (lrow & 7) << 4;
  float denp = 0.f;
#pragma unroll
  for (int mw = 0; mw < 4; ++mw) {
    float mm[4];
    if (mbyte) {
#pragma unroll
      for (int r = 0; r < 4; ++r)
        mm[r] = (float)(((mdm[mw] >> (8 * r)) & 0xFFu) ? 1 : 0);
    } else {
      const int w0 = wbase + mw * 16 + g * 4;
      uint4 mi = (fok && w0 < Wdim)
                     ? *(const uint4*)(mask_i + (size_t)f_m * Wdim + w0)
                     : make_uint4(0u, 0u, 0u, 0u);
      mm[0] = mi.x ? 1.f : 0.f;
      mm[1] = mi.y ? 1.f : 0.f;
      mm[2] = mi.z ? 1.f : 0.f;
      mm[3] = mi.w ? 1.f : 0.f;
    }
    float v[4];
#pragma unroll
    for (int r = 0; r < 4; ++r) {
      v[r] = fast_exp2(accT[mw][r] * kLog2e) * mm[r];
      denp += v[r];
    }
    const int wb0 = (mw * 16 + g * 4) * 2;
    *(f16x2*)(sbase + lrow * 128 + ((wb0 + 0) ^ sw)) = pack_f16(v[0], v[1]);
    *(f16x2*)(sbase + lrow * 128 + ((wb0 + 4) ^ sw)) = pack_f16(v[2], v[3]);
  }

  // ---- second GEMM: num[16f][16e] over this wave's 64 w
  f32x4 numT = (f32x4){0.f, 0.f, 0.f, 0.f};
  {
    const f16x8 scf0 =
        *(const f16x8*)(sbase + lrow * 128 + ((0 * 64 + g * 16) ^ sw));
    numT = __builtin_amdgcn_mfma_f32_16x16x32_f16(scf0, hb0, numT, 0, 0, 0);
    const f16x8 scf1 =
        *(const f16x8*)(sbase + lrow * 128 + ((1 * 64 + g * 16) ^ sw));
    numT = __builtin_amdgcn_mfma_f32_16x16x32_f16(scf1, hb1, numT, 0, 0, 0);
  }

  // ---- den: sum across the 4 lane-groups (same f, different g)
  denp += __shfl_xor(denp, 16, 64);
  denp += __shfl_xor(denp, 32, 64);

  // ---- write partials for this 64-w chunk
  const int chunk = bx * 2 + wc;
  if (lane < 16) part_den[(size_t)chunk * Mp + fbase + lrow] = denp;
#pragma unroll
  for (int r = 0; r < 4; ++r) {
    const int f = fbase + g * 4 + r;
    part_num[((size_t)chunk * Mp + f) * Edim + lrow] = numT[r];
  }
}

// finalize: ctx[f][e] = sum_c num / sum_c den
__global__ __launch_bounds__(256) void finalize2_kernel(
    const float* __restrict__ part_num, const float* __restrict__ part_den,
    float* __restrict__ ctx) {
  int idx = blockIdx.x * 256 + threadIdx.x;
  if (idx >= Fdim * Edim) return;
  int f = idx >> 4, e = idx & 15;
  float num = 0.f, den = 0.f;
#pragma unroll 4
  for (int c = 0; c < NCHUNK; ++c) {
    num += part_num[((size_t)c * Mp + f) * Edim + e];
    den += part_den[(size_t)c * Mp + f];
  }
  ctx[idx] = num / den;
}

// out[b][e] = sum_f values[b][f] * ctx[f][e]
__global__ __launch_bounds__(256) void out_gemv_kernel(
    const float* __restrict__ values, const float* __restrict__ ctx,
    float* __restrict__ out) {
  const int b = blockIdx.x, tid = threadIdx.x;
  float acc[Edim];
#pragma unroll
  for (int e = 0; e < Edim; ++e) acc[e] = 0.f;
  for (int f = tid; f < Fdim; f += 256) {
    float v = values[b * Fdim + f];
    const float4* c4 = (const float4*)(ctx + f * Edim);
    float4 c0 = c4[0], c1 = c4[1], c2 = c4[2], c3 = c4[3];
    float cr[Edim] = {c0.x, c0.y, c0.z, c0.w, c1.x, c1.y, c1.z, c1.w,
                      c2.x, c2.y, c2.z, c2.w, c3.x, c3.y, c3.z, c3.w};
#pragma unroll
    for (int e = 0; e < Edim; ++e) acc[e] = fmaf(v, cr[e], acc[e]);
  }
  __shared__ float s_red[4][Edim];
  const int lane = tid & 63, wv = tid >> 6;
#pragma unroll
  for (int e = 0; e < Edim; ++e) {
    float a = wave64_sum(acc[e]);
    if (lane == 63) s_red[wv][e] = a;
  }
  __syncthreads();
  if (tid < Edim)
    out[b * Edim + tid] =
        s_red[0][tid] + s_red[1][tid] + s_red[2][tid] + s_red[3][tid];
}

extern "C" void kernel_launch(void* const* d_in, const int* in_sizes, int n_in,
                              void* d_out, int out_size, void* d_ws,
                              size_t ws_size, hipStream_t stream) {
  const float* values = (const float*)d_in[0];
  const float* femb   = (const float*)d_in[1];
  const float* hemb   = (const float*)d_in[2];
  const float* Ww     = (const float*)d_in[3];
  const float* bw     = (const float*)d_in[4];
  const float* Wu     = (const float*)d_in[5];
  const unsigned char* mask = (const unsigned char*)d_in[6];
  float* out = (float*)d_out;
  float* ws = (float*)d_ws;

  // ws layout (float units). Total ~13 MB.
  const size_t OFF_FLG = 0;                                  // 16
  const size_t OFF_A = 16;                                   // Mp*Kp/2 = 327680
  const size_t OFF_B = OFF_A + (size_t)Mp * Kp / 2;          // Np*Kp/2 = 655360
  const size_t OFF_HB = OFF_B + (size_t)Np * Kp / 2;         // 32768
  const size_t OFF_PN = OFF_HB + 32768;                      // 64*2048*16 = 2097152
  const size_t OFF_PD = OFF_PN + (size_t)NCHUNK * Mp * Edim; // 131072
  const size_t OFF_CTX = OFF_PD + (size_t)NCHUNK * Mp;       // 32000

  int* mflag = (int*)(ws + OFF_FLG);
  _Float16* A = (_Float16*)(ws + OFF_A);
  _Float16* B = (_Float16*)(ws + OFF_B);
  _Float16* hembB = (_Float16*)(ws + OFF_HB);
  float* part_num = ws + OFF_PN;
  float* part_den = ws + OFF_PD;
  float* ctx = ws + OFF_CTX;

  constexpr int PTOT = Fdim * Hdim + (Mp - Fdim) * Kp / 2 + Wdim * Hdim +
                       (Np - Wdim) * Kp / 2 + (Np / 32) * 64 + 64;  // 415296
  prep2_kernel<<<dim3((PTOT + 255) / 256), dim3(256), 0, stream>>>(
      femb, hemb, Ww, bw, Wu, mask, A, B, hembB, mflag);

  score_ctx_kernel<<<dim3(Np / 128, Mp / 32), dim3(256), 0, stream>>>(
      A, B, mask, mflag, hembB, part_num, part_den);

  finalize2_kernel<<<dim3((Fdim * Edim + 255) / 256), dim3(256), 0, stream>>>(
      part_num, part_den, ctx);

  out_gemv_kernel<<<dim3(Bdim), dim3(256), 0, stream>>>(values, ctx, out);
}

// Round 14
// 90.114 us; speedup vs baseline: 1.1022x; 1.1022x over previous
//
#include <hip/hip_runtime.h>

constexpr int Fdim = 2000;
constexpr int Wdim = 4000;
constexpr int Edim = 16;
constexpr int Hdim = 64;
constexpr int Bdim = 256;
constexpr float kLog2e = 1.4426950408889634f;

// ---- MFMA-path padded dims
constexpr int Mp = 2048;        // padded F
constexpr int Np = 4096;        // padded W
constexpr int Kp = 320;         // 5 tanh powers x 64 h
constexpr int NCHUNK = Np / 64; // 64 w-chunks of partials

typedef _Float16 f16x8 __attribute__((ext_vector_type(8)));
typedef _Float16 f16x2 __attribute__((ext_vector_type(2)));
typedef float f32x4 __attribute__((ext_vector_type(4)));

__device__ __forceinline__ float fast_exp2(float x) {
#if __has_builtin(__builtin_amdgcn_exp2f)
  return __builtin_amdgcn_exp2f(x);
#else
  return exp2f(x);
#endif
}
__device__ __forceinline__ float fast_rcp(float x) {
#if __has_builtin(__builtin_amdgcn_rcpf)
  return __builtin_amdgcn_rcpf(x);
#else
  return 1.0f / x;
#endif
}
__device__ __forceinline__ float dev_tanh(float x) {
  return 1.0f - 2.0f * fast_rcp(fast_exp2(2.0f * kLog2e * x) + 1.0f);
}
__device__ __forceinline__ f16x2 pack_f16(float a, float b) {
  return __builtin_bit_cast(f16x2, __builtin_amdgcn_cvt_pkrtz(a, b));
}

// ---- DPP wave-64 sum (VALU pipe). Result valid in lane 63.
template <int CTRL>
__device__ __forceinline__ float dpp_part(float x) {
  return __int_as_float(
      __builtin_amdgcn_update_dpp(0, __float_as_int(x), CTRL, 0xF, 0xF, true));
}
__device__ __forceinline__ float wave64_sum(float x) {
  const float x0 = x;
  x += dpp_part<0x111>(x0);
  x += dpp_part<0x112>(x0);
  x += dpp_part<0x113>(x0);
  x += dpp_part<0x114>(x);
  x += dpp_part<0x118>(x);
  x += dpp_part<0x142>(x);
  x += dpp_part<0x143>(x);
  return x;
}

// prep2: fp16 GEMM operands + hemb B-fragments + fused mask-layout detect.
//   A[f][j*64+h] = tanh(s)^j (j=0..4), s = femb@Ww[:E]; rows >=Fdim zeroed
//   B[w][j*64+h] = Wu[h]*{q,1-q^2,q^3-q,q^2-q^4,-q^3}, q=tanh(hid+b); pad 0
//   hembB[widx][lane][i] = hemb[widx*32+(lane>>4)*8+i][lane&15]  (fp16 frags)
//   mflag = 1 if mask is 1-byte bool layout, 0 if int32.
__global__ __launch_bounds__(256) void prep2_kernel(
    const float* __restrict__ femb, const float* __restrict__ hemb,
    const float* __restrict__ Ww, const float* __restrict__ bw,
    const float* __restrict__ Wu, const unsigned char* __restrict__ mask,
    _Float16* __restrict__ A, _Float16* __restrict__ B,
    _Float16* __restrict__ hembB, int* __restrict__ mflag) {
  constexpr int PA = Fdim * Hdim;                  // 128000 A main
  constexpr int PAZ = PA + (Mp - Fdim) * Kp / 2;   // +7680 A pad (u32)
  constexpr int PB = PAZ + Wdim * Hdim;            // +256000 B main
  constexpr int PBZ = PB + (Np - Wdim) * Kp / 2;   // +15360 B pad (u32)
  constexpr int PH = PBZ + (Np / 32) * 64;         // +8192 hembB
  constexpr int PD = PH + 64;                      // +64 detect wave
  int idx = blockIdx.x * 256 + threadIdx.x;
  if (idx < PA) {
    int f = idx >> 6, h = idx & 63;
    float s = 0.f;
#pragma unroll
    for (int e = 0; e < Edim; ++e)
      s = fmaf(femb[f * Edim + e], Ww[e * Hdim + h], s);
    float p = dev_tanh(s);
    _Float16* a = A + (size_t)f * Kp + h;
    float pj = 1.0f;
#pragma unroll
    for (int j = 0; j < 5; ++j) {
      a[j * 64] = (_Float16)pj;
      pj *= p;
    }
  } else if (idx < PAZ) {
    ((unsigned int*)(A + (size_t)Fdim * Kp))[idx - PA] = 0u;
  } else if (idx < PB) {
    int jj = idx - PAZ;
    int w = jj >> 6, h = jj & 63;
    float t = bw[h];
#pragma unroll
    for (int e = 0; e < Edim; ++e)
      t = fmaf(hemb[w * Edim + e], Ww[(Edim + e) * Hdim + h], t);
    float q = dev_tanh(t);
    float wu = Wu[h];
    float q2 = q * q, q3 = q2 * q;
    _Float16* b = B + (size_t)w * Kp + h;
    b[0 * 64] = (_Float16)(wu * q);
    b[1 * 64] = (_Float16)(wu * (1.0f - q2));
    b[2 * 64] = (_Float16)(wu * (q3 - q));
    b[3 * 64] = (_Float16)(wu * (q2 - q2 * q2));
    b[4 * 64] = (_Float16)(-wu * q3);
  } else if (idx < PBZ) {
    ((unsigned int*)(B + (size_t)Wdim * Kp))[idx - PB] = 0u;
  } else if (idx < PH) {
    int j = idx - PBZ;
    int lane = j & 63;
    int e = lane & 15;
    int wb = (j >> 6) * 32 + (lane >> 4) * 8;
    f16x8 v;
#pragma unroll
    for (int i = 0; i < 8; ++i) {
      int w = wb + i;
      v[i] = (w < Wdim) ? (_Float16)hemb[(size_t)w * Edim + e] : (_Float16)0.f;
    }
    *(f16x8*)(hembB + (size_t)j * 8) = v;
  } else if (idx < PD) {
    // mask layout detect: bytes at i%4!=0 all zero <=> int32 layout
    int l = idx - PH;
    int acc = 0;
    for (int i = l; i < 8192; i += 64)
      if ((i & 3) != 0) acc |= mask[i];
    unsigned long long bl = __ballot(acc != 0);
    if (l == 0) *mflag = (bl != 0ull) ? 1 : 0;
  }
}

// score_ctx: fused, 16f x 64w per wave, 2048 blocks, XCD-swizzled.
// NO min-waves clamp: VGPR floats to its natural ~50 so the K-loop keeps
// full memory-level parallelism (R13 lesson: the (256,8) clamp collapsed
// MLP at VGPR=32 and cost 40%).
// First GEMM SWAPPED: mfma(B_w, A_f) -> D col=f (lane&15), row=w.
// Mask + hembB prefetched BEFORE the K-loop (latency hides under MFMA).
// Epilogue: exp2*mask -> fp16 -> per-wave XOR-swizzled LDS tile [16f][64w].
// Second GEMM contracts w -> num[16f][16e]; den via in-reg sum + shfl_xor.
__global__ __launch_bounds__(256) void score_ctx_kernel(
    const _Float16* __restrict__ A, const _Float16* __restrict__ B,
    const unsigned char* __restrict__ mask_b, const int* __restrict__ mflag,
    const _Float16* __restrict__ hembB,
    float* __restrict__ part_num, float* __restrict__ part_den) {
  __shared__ __align__(16) char smem[8192];  // 2 KB per wave
  const int tid = threadIdx.x;
  const int wid = tid >> 6, lane = tid & 63;
  const int wr = wid >> 1, wc = wid & 1;

  // ---- bijective XCD swizzle (2048 blocks, 8 XCDs): XCD c gets 4
  // consecutive w-tiles x all 64 f-tiles -> per-XCD L2 set ~1.6 MB.
  const int lin = blockIdx.y * 32 + blockIdx.x;   // grid (32, 64)
  const int nl = (lin & 7) * 256 + (lin >> 3);
  const int bx = nl >> 6;   // w-tile (128 w) index [0,32)
  const int by = nl & 63;   // f-tile (32 f) index [0,64)

  const int fbase = by * 32 + wr * 16;
  const int wbase = bx * 128 + wc * 64;
  const int lrow = lane & 15, g = lane >> 4;

  // ---- EARLY issue: mask (byte-layout fast path) + hembB fragments
  const int mbyte = *mflag;  // uniform s_load
  const int f_m = fbase + lrow;
  const bool fok = (f_m < Fdim);
  unsigned int mdm[4];
  if (mbyte) {
#pragma unroll
    for (int mw = 0; mw < 4; ++mw) {
      const int w0 = wbase + mw * 16 + g * 4;
      mdm[mw] = (fok && w0 < Wdim)
                    ? *(const unsigned int*)(mask_b + (size_t)f_m * Wdim + w0)
                    : 0u;
    }
  }
  const f16x8 hb0 =
      *(const f16x8*)(hembB + ((size_t)(wbase >> 5) + 0) * 512 + lane * 8);
  const f16x8 hb1 =
      *(const f16x8*)(hembB + ((size_t)(wbase >> 5) + 1) * 512 + lane * 8);

  // ---- first GEMM: accT[mw] = sc^T frags (col=f, row=w)
  f32x4 accT[4];
#pragma unroll
  for (int mw = 0; mw < 4; ++mw) accT[mw] = (f32x4){0.f, 0.f, 0.f, 0.f};

  const _Float16* Bw = B + (size_t)(wbase + lrow) * Kp + g * 8;
  const _Float16* Af = A + (size_t)(fbase + lrow) * Kp + g * 8;
#pragma unroll 2
  for (int ks = 0; ks < Kp / 32; ++ks) {
    f16x8 bw[4];
#pragma unroll
    for (int mw = 0; mw < 4; ++mw)
      bw[mw] = *(const f16x8*)(Bw + (size_t)mw * 16 * Kp + ks * 32);
    const f16x8 af = *(const f16x8*)(Af + ks * 32);
#pragma unroll
    for (int mw = 0; mw < 4; ++mw)
      accT[mw] =
          __builtin_amdgcn_mfma_f32_16x16x32_f16(bw[mw], af, accT[mw], 0, 0, 0);
  }

  // ---- epilogue: exp2 * mask -> fp16 -> swizzled LDS; den partial
  const int* mask_i = (const int*)mask_b;
  char* sbase = smem + wid * 2048;
  const int sw = (lrow & 7) << 4;
  float denp = 0.f;
#pragma unroll
  for (int mw = 0; mw < 4; ++mw) {
    float mm[4];
    if (mbyte) {
#pragma unroll
      for (int r = 0; r < 4; ++r)
        mm[r] = (float)(((mdm[mw] >> (8 * r)) & 0xFFu) ? 1 : 0);
    } else {
      const int w0 = wbase + mw * 16 + g * 4;
      uint4 mi = (fok && w0 < Wdim)
                     ? *(const uint4*)(mask_i + (size_t)f_m * Wdim + w0)
                     : make_uint4(0u, 0u, 0u, 0u);
      mm[0] = mi.x ? 1.f : 0.f;
      mm[1] = mi.y ? 1.f : 0.f;
      mm[2] = mi.z ? 1.f : 0.f;
      mm[3] = mi.w ? 1.f : 0.f;
    }
    float v[4];
#pragma unroll
    for (int r = 0; r < 4; ++r) {
      v[r] = fast_exp2(accT[mw][r] * kLog2e) * mm[r];
      denp += v[r];
    }
    const int wb0 = (mw * 16 + g * 4) * 2;
    *(f16x2*)(sbase + lrow * 128 + ((wb0 + 0) ^ sw)) = pack_f16(v[0], v[1]);
    *(f16x2*)(sbase + lrow * 128 + ((wb0 + 4) ^ sw)) = pack_f16(v[2], v[3]);
  }

  // ---- second GEMM: num[16f][16e] over this wave's 64 w
  f32x4 numT = (f32x4){0.f, 0.f, 0.f, 0.f};
  {
    const f16x8 scf0 =
        *(const f16x8*)(sbase + lrow * 128 + ((0 * 64 + g * 16) ^ sw));
    numT = __builtin_amdgcn_mfma_f32_16x16x32_f16(scf0, hb0, numT, 0, 0, 0);
    const f16x8 scf1 =
        *(const f16x8*)(sbase + lrow * 128 + ((1 * 64 + g * 16) ^ sw));
    numT = __builtin_amdgcn_mfma_f32_16x16x32_f16(scf1, hb1, numT, 0, 0, 0);
  }

  // ---- den: sum across the 4 lane-groups (same f, different g)
  denp += __shfl_xor(denp, 16, 64);
  denp += __shfl_xor(denp, 32, 64);

  // ---- write partials for this 64-w chunk
  const int chunk = bx * 2 + wc;
  if (lane < 16) part_den[(size_t)chunk * Mp + fbase + lrow] = denp;
#pragma unroll
  for (int r = 0; r < 4; ++r) {
    const int f = fbase + g * 4 + r;
    part_num[((size_t)chunk * Mp + f) * Edim + lrow] = numT[r];
  }
}

// finalize: ctx[f][e] = sum_c num / sum_c den
__global__ __launch_bounds__(256) void finalize2_kernel(
    const float* __restrict__ part_num, const float* __restrict__ part_den,
    float* __restrict__ ctx) {
  int idx = blockIdx.x * 256 + threadIdx.x;
  if (idx >= Fdim * Edim) return;
  int f = idx >> 4, e = idx & 15;
  float num = 0.f, den = 0.f;
#pragma unroll 4
  for (int c = 0; c < NCHUNK; ++c) {
    num += part_num[((size_t)c * Mp + f) * Edim + e];
    den += part_den[(size_t)c * Mp + f];
  }
  ctx[idx] = num / den;
}

// out[b][e] = sum_f values[b][f] * ctx[f][e]
__global__ __launch_bounds__(256) void out_gemv_kernel(
    const float* __restrict__ values, const float* __restrict__ ctx,
    float* __restrict__ out) {
  const int b = blockIdx.x, tid = threadIdx.x;
  float acc[Edim];
#pragma unroll
  for (int e = 0; e < Edim; ++e) acc[e] = 0.f;
  for (int f = tid; f < Fdim; f += 256) {
    float v = values[b * Fdim + f];
    const float4* c4 = (const float4*)(ctx + f * Edim);
    float4 c0 = c4[0], c1 = c4[1], c2 = c4[2], c3 = c4[3];
    float cr[Edim] = {c0.x, c0.y, c0.z, c0.w, c1.x, c1.y, c1.z, c1.w,
                      c2.x, c2.y, c2.z, c2.w, c3.x, c3.y, c3.z, c3.w};
#pragma unroll
    for (int e = 0; e < Edim; ++e) acc[e] = fmaf(v, cr[e], acc[e]);
  }
  __shared__ float s_red[4][Edim];
  const int lane = tid & 63, wv = tid >> 6;
#pragma unroll
  for (int e = 0; e < Edim; ++e) {
    float a = wave64_sum(acc[e]);
    if (lane == 63) s_red[wv][e] = a;
  }
  __syncthreads();
  if (tid < Edim)
    out[b * Edim + tid] =
        s_red[0][tid] + s_red[1][tid] + s_red[2][tid] + s_red[3][tid];
}

extern "C" void kernel_launch(void* const* d_in, const int* in_sizes, int n_in,
                              void* d_out, int out_size, void* d_ws,
                              size_t ws_size, hipStream_t stream) {
  const float* values = (const float*)d_in[0];
  const float* femb   = (const float*)d_in[1];
  const float* hemb   = (const float*)d_in[2];
  const float* Ww     = (const float*)d_in[3];
  const float* bw     = (const float*)d_in[4];
  const float* Wu     = (const float*)d_in[5];
  const unsigned char* mask = (const unsigned char*)d_in[6];
  float* out = (float*)d_out;
  float* ws = (float*)d_ws;

  // ws layout (float units). Total ~13 MB.
  const size_t OFF_FLG = 0;                                  // 16
  const size_t OFF_A = 16;                                   // Mp*Kp/2 = 327680
  const size_t OFF_B = OFF_A + (size_t)Mp * Kp / 2;          // Np*Kp/2 = 655360
  const size_t OFF_HB = OFF_B + (size_t)Np * Kp / 2;         // 32768
  const size_t OFF_PN = OFF_HB + 32768;                      // 64*2048*16 = 2097152
  const size_t OFF_PD = OFF_PN + (size_t)NCHUNK * Mp * Edim; // 131072
  const size_t OFF_CTX = OFF_PD + (size_t)NCHUNK * Mp;       // 32000

  int* mflag = (int*)(ws + OFF_FLG);
  _Float16* A = (_Float16*)(ws + OFF_A);
  _Float16* B = (_Float16*)(ws + OFF_B);
  _Float16* hembB = (_Float16*)(ws + OFF_HB);
  float* part_num = ws + OFF_PN;
  float* part_den = ws + OFF_PD;
  float* ctx = ws + OFF_CTX;

  constexpr int PTOT = Fdim * Hdim + (Mp - Fdim) * Kp / 2 + Wdim * Hdim +
                       (Np - Wdim) * Kp / 2 + (Np / 32) * 64 + 64;  // 415296
  prep2_kernel<<<dim3((PTOT + 255) / 256), dim3(256), 0, stream>>>(
      femb, hemb, Ww, bw, Wu, mask, A, B, hembB, mflag);

  score_ctx_kernel<<<dim3(Np / 128, Mp / 32), dim3(256), 0, stream>>>(
      A, B, mask, mflag, hembB, part_num, part_den);

  finalize2_kernel<<<dim3((Fdim * Edim + 255) / 256), dim3(256), 0, stream>>>(
      part_num, part_den, ctx);

  out_gemv_kernel<<<dim3(Bdim), dim3(256), 0, stream>>>(values, ctx, out);
}

// Round 15
// 58.870 us; speedup vs baseline: 1.6872x; 1.5307x over previous
//
#include <hip/hip_runtime.h>

constexpr int Fdim = 2000;
constexpr int Wdim = 4000;
constexpr int Edim = 16;
constexpr int Hdim = 64;
constexpr int Bdim = 256;
constexpr float kLog2e = 1.4426950408889634f;

// ---- MFMA-path padded dims
constexpr int Mp = 2048;        // padded F
constexpr int Np = 4096;        // padded W
constexpr int NKS = 10;         // 320 / 32 k-steps
constexpr int NWRD = Np / 32;   // 128 mask words per row
constexpr int NCHUNK = Np / 64; // 64 w-chunks of partials

typedef _Float16 f16x8 __attribute__((ext_vector_type(8)));
typedef _Float16 f16x2 __attribute__((ext_vector_type(2)));
typedef float f32x4 __attribute__((ext_vector_type(4)));

__device__ __forceinline__ float fast_exp2(float x) {
#if __has_builtin(__builtin_amdgcn_exp2f)
  return __builtin_amdgcn_exp2f(x);
#else
  return exp2f(x);
#endif
}
__device__ __forceinline__ float fast_rcp(float x) {
#if __has_builtin(__builtin_amdgcn_rcpf)
  return __builtin_amdgcn_rcpf(x);
#else
  return 1.0f / x;
#endif
}
__device__ __forceinline__ float dev_tanh(float x) {
  return 1.0f - 2.0f * fast_rcp(fast_exp2(2.0f * kLog2e * x) + 1.0f);
}
__device__ __forceinline__ f16x2 pack_f16(float a, float b) {
  return __builtin_bit_cast(f16x2, __builtin_amdgcn_cvt_pkrtz(a, b));
}

// ---- DPP wave-64 sum (VALU pipe). Result valid in lane 63.
template <int CTRL>
__device__ __forceinline__ float dpp_part(float x) {
  return __int_as_float(
      __builtin_amdgcn_update_dpp(0, __float_as_int(x), CTRL, 0xF, 0xF, true));
}
__device__ __forceinline__ float wave64_sum(float x) {
  const float x0 = x;
  x += dpp_part<0x111>(x0);
  x += dpp_part<0x112>(x0);
  x += dpp_part<0x113>(x0);
  x += dpp_part<0x114>(x);
  x += dpp_part<0x118>(x);
  x += dpp_part<0x142>(x);
  x += dpp_part<0x143>(x);
  return x;
}

// --- detect whether mask is 1-byte bool or 4-byte int32 -------------------
__global__ void detect_mask_kernel(const unsigned char* __restrict__ mask,
                                   int* __restrict__ flag) {
  __shared__ int any;
  if (threadIdx.x == 0) any = 0;
  __syncthreads();
  int acc = 0;
  for (int i = threadIdx.x; i < 8192; i += 256)
    if ((i & 3) != 0) acc |= mask[i];
  if (acc) atomicOr(&any, 1);
  __syncthreads();
  if (threadIdx.x == 0) *flag = (any != 0) ? 1 : 0;  // 1 = byte layout
}

// prep2: FRAGMENT-MAJOR fp16 operands + bit-packed mask + hemb fragments.
//   A2[ftile][ks][lane][i] (f16x8 per lane): lane = g*16 + (f&15) holds
//     A[f][k= ks*32+g*8+i] = tanh(s)^j decomposed k = j*64+h.
//   B2[wtile][ks][lane][i] likewise for B[w][k] = Wu[h]*poly_j(q).
//   -> every score_ctx K-loop load is a contiguous 1KB wave-burst.
//   mbits[f][word] bit j <=> mask[f][word*32+j]; pad rows/words zero.
//   hembB: fragment-major hemb (fp16).
__global__ __launch_bounds__(256) void prep2_kernel(
    const float* __restrict__ femb, const float* __restrict__ hemb,
    const float* __restrict__ Ww, const float* __restrict__ bw,
    const float* __restrict__ Wu, const unsigned char* __restrict__ mask,
    const int* __restrict__ mflag, _Float16* __restrict__ A2,
    _Float16* __restrict__ B2, unsigned int* __restrict__ mbits,
    _Float16* __restrict__ hembB) {
  constexpr int PA = Fdim * Hdim;                  // 128000 A main
  constexpr int PAZ = PA + 3 * NKS * 512 / 2;      // +7680 A pad (u32): ftile 125-127
  constexpr int PB = PAZ + Wdim * Hdim;            // +256000 B main
  constexpr int PBZ = PB + 6 * NKS * 512 / 2;      // +15360 B pad (u32): wtile 250-255
  constexpr int PM = PBZ + Mp * NWRD;              // +262144 mbits
  constexpr int PH = PM + (Np / 32) * 64;          // +8192 hembB
  int idx = blockIdx.x * 256 + threadIdx.x;
  if (idx < PA) {
    int f = idx >> 6, h = idx & 63;
    float s = 0.f;
#pragma unroll
    for (int e = 0; e < Edim; ++e)
      s = fmaf(femb[f * Edim + e], Ww[e * Hdim + h], s);
    float p = dev_tanh(s);
    const int lane = ((h & 31) >> 3) * 16 + (f & 15);
    const int base = (f >> 4) * NKS + (h >> 5);   // + j*2 per power
    float pj = 1.0f;
#pragma unroll
    for (int j = 0; j < 5; ++j) {
      A2[(size_t)(base + 2 * j) * 512 + lane * 8 + (h & 7)] = (_Float16)pj;
      pj *= p;
    }
  } else if (idx < PAZ) {
    ((unsigned int*)(A2 + (size_t)125 * NKS * 512))[idx - PA] = 0u;
  } else if (idx < PB) {
    int jj = idx - PAZ;
    int w = jj >> 6, h = jj & 63;
    float t = bw[h];
#pragma unroll
    for (int e = 0; e < Edim; ++e)
      t = fmaf(hemb[w * Edim + e], Ww[(Edim + e) * Hdim + h], t);
    float q = dev_tanh(t);
    float wu = Wu[h];
    float q2 = q * q, q3 = q2 * q;
    float bv[5] = {wu * q, wu * (1.0f - q2), wu * (q3 - q),
                   wu * (q2 - q2 * q2), -wu * q3};
    const int lane = ((h & 31) >> 3) * 16 + (w & 15);
    const int base = (w >> 4) * NKS + (h >> 5);
#pragma unroll
    for (int j = 0; j < 5; ++j)
      B2[(size_t)(base + 2 * j) * 512 + lane * 8 + (h & 7)] = (_Float16)bv[j];
  } else if (idx < PBZ) {
    ((unsigned int*)(B2 + (size_t)250 * NKS * 512))[idx - PB] = 0u;
  } else if (idx < PM) {
    int t = idx - PBZ;
    int f = t >> 7, word = t & 127;
    unsigned int bits = 0u;
    if (f < Fdim && word < Wdim / 32) {
      const int w0 = word * 32;
      if (*mflag) {  // byte layout: 32 bytes -> 2 uint4
        const uint4* p = (const uint4*)(mask + (size_t)f * Wdim + w0);
        uint4 u0 = p[0], u1 = p[1];
        unsigned int uu[8] = {u0.x, u0.y, u0.z, u0.w, u1.x, u1.y, u1.z, u1.w};
#pragma unroll
        for (int k = 0; k < 8; ++k)
#pragma unroll
          for (int b2 = 0; b2 < 4; ++b2)
            bits |= (((uu[k] >> (8 * b2)) & 0xFFu) ? 1u : 0u) << (k * 4 + b2);
      } else {       // int32 layout: 32 ints -> 8 uint4
        const uint4* p =
            (const uint4*)((const unsigned int*)mask + (size_t)f * Wdim + w0);
#pragma unroll
        for (int k = 0; k < 8; ++k) {
          uint4 u = p[k];
          bits |= (u.x ? 1u : 0u) << (4 * k + 0);
          bits |= (u.y ? 1u : 0u) << (4 * k + 1);
          bits |= (u.z ? 1u : 0u) << (4 * k + 2);
          bits |= (u.w ? 1u : 0u) << (4 * k + 3);
        }
      }
    }
    mbits[(size_t)f * NWRD + word] = bits;
  } else if (idx < PH) {
    int j = idx - PM;
    int lane = j & 63;
    int e = lane & 15;
    int wb = (j >> 6) * 32 + (lane >> 4) * 8;
    f16x8 v;
#pragma unroll
    for (int i = 0; i < 8; ++i) {
      int w = wb + i;
      v[i] = (w < Wdim) ? (_Float16)hemb[(size_t)w * Edim + e] : (_Float16)0.f;
    }
    *(f16x8*)(hembB + (size_t)j * 8) = v;
  }
}

// score_ctx: fused, 16f x 64w per wave, 2048 blocks, XCD-swizzled.
// ALL global loads contiguous: A2/B2 fragment-major (1KB wave-bursts),
// mask via 8B mbits uint2 (1MB L2-resident). Early issue of mbits+hembB.
// First GEMM SWAPPED: mfma(B_w, A_f) -> D col=f, row=w. Epilogue:
// exp2*maskbit -> fp16 -> per-wave XOR-swizzled LDS tile. Second GEMM
// contracts w -> num[16f][16e]; den via in-reg sum + shfl_xor.
__global__ __launch_bounds__(256) void score_ctx_kernel(
    const _Float16* __restrict__ A2, const _Float16* __restrict__ B2,
    const unsigned int* __restrict__ mbits, const _Float16* __restrict__ hembB,
    float* __restrict__ part_num, float* __restrict__ part_den) {
  __shared__ __align__(16) char smem[8192];  // 2 KB per wave
  const int tid = threadIdx.x;
  const int wid = tid >> 6, lane = tid & 63;
  const int wr = wid >> 1, wc = wid & 1;

  // ---- bijective XCD swizzle (2048 blocks, 8 XCDs): XCD c gets 4
  // consecutive w-tiles x all 64 f-tiles.
  const int lin = blockIdx.y * 32 + blockIdx.x;   // grid (32, 64)
  const int nl = (lin & 7) * 256 + (lin >> 3);
  const int bx = nl >> 6;   // w-tile (128 w) index [0,32)
  const int by = nl & 63;   // f-tile (32 f) index [0,64)

  const int fbase = by * 32 + wr * 16;
  const int wbase = bx * 128 + wc * 64;
  const int lrow = lane & 15, g = lane >> 4;

  // ---- EARLY issue: mask bits (8B/lane) + hembB fragments
  const uint2 mb =
      *(const uint2*)(mbits + (size_t)(fbase + lrow) * NWRD + (wbase >> 5));
  const f16x8 hb0 =
      *(const f16x8*)(hembB + ((size_t)(wbase >> 5) + 0) * 512 + lane * 8);
  const f16x8 hb1 =
      *(const f16x8*)(hembB + ((size_t)(wbase >> 5) + 1) * 512 + lane * 8);

  // ---- first GEMM: accT[mw] = sc^T frags (col=f, row=w)
  f32x4 accT[4];
#pragma unroll
  for (int mw = 0; mw < 4; ++mw) accT[mw] = (f32x4){0.f, 0.f, 0.f, 0.f};

  const _Float16* Ab = A2 + ((size_t)(fbase >> 4) * NKS) * 512 + lane * 8;
  const _Float16* Bb = B2 + ((size_t)(wbase >> 4) * NKS) * 512 + lane * 8;
#pragma unroll 2
  for (int ks = 0; ks < NKS; ++ks) {
    f16x8 bw[4];
#pragma unroll
    for (int mw = 0; mw < 4; ++mw)
      bw[mw] = *(const f16x8*)(Bb + (size_t)(mw * NKS + ks) * 512);
    const f16x8 af = *(const f16x8*)(Ab + (size_t)ks * 512);
#pragma unroll
    for (int mw = 0; mw < 4; ++mw)
      accT[mw] =
          __builtin_amdgcn_mfma_f32_16x16x32_f16(bw[mw], af, accT[mw], 0, 0, 0);
  }

  // ---- epilogue: exp2 * maskbit -> fp16 -> swizzled LDS; den partial
  char* sbase = smem + wid * 2048;
  const int sw = (lrow & 7) << 4;
  float denp = 0.f;
#pragma unroll
  for (int mw = 0; mw < 4; ++mw) {
    float v[4];
#pragma unroll
    for (int r = 0; r < 4; ++r) {
      const int wl = mw * 16 + g * 4 + r;
      const unsigned int word = (wl < 32) ? mb.x : mb.y;
      const float m = (float)((word >> (wl & 31)) & 1u);
      v[r] = fast_exp2(accT[mw][r] * kLog2e) * m;
      denp += v[r];
    }
    const int wb0 = (mw * 16 + g * 4) * 2;
    *(f16x2*)(sbase + lrow * 128 + ((wb0 + 0) ^ sw)) = pack_f16(v[0], v[1]);
    *(f16x2*)(sbase + lrow * 128 + ((wb0 + 4) ^ sw)) = pack_f16(v[2], v[3]);
  }

  // ---- second GEMM: num[16f][16e] over this wave's 64 w
  f32x4 numT = (f32x4){0.f, 0.f, 0.f, 0.f};
  {
    const f16x8 scf0 =
        *(const f16x8*)(sbase + lrow * 128 + ((0 * 64 + g * 16) ^ sw));
    numT = __builtin_amdgcn_mfma_f32_16x16x32_f16(scf0, hb0, numT, 0, 0, 0);
    const f16x8 scf1 =
        *(const f16x8*)(sbase + lrow * 128 + ((1 * 64 + g * 16) ^ sw));
    numT = __builtin_amdgcn_mfma_f32_16x16x32_f16(scf1, hb1, numT, 0, 0, 0);
  }

  // ---- den: sum across the 4 lane-groups (same f, different g)
  denp += __shfl_xor(denp, 16, 64);
  denp += __shfl_xor(denp, 32, 64);

  // ---- write partials for this 64-w chunk
  const int chunk = bx * 2 + wc;
  if (lane < 16) part_den[(size_t)chunk * Mp + fbase + lrow] = denp;
#pragma unroll
  for (int r = 0; r < 4; ++r) {
    const int f = fbase + g * 4 + r;
    part_num[((size_t)chunk * Mp + f) * Edim + lrow] = numT[r];
  }
}

// finalize: ctx[f][e] = sum_c num / sum_c den
__global__ __launch_bounds__(256) void finalize2_kernel(
    const float* __restrict__ part_num, const float* __restrict__ part_den,
    float* __restrict__ ctx) {
  int idx = blockIdx.x * 256 + threadIdx.x;
  if (idx >= Fdim * Edim) return;
  int f = idx >> 4, e = idx & 15;
  float num = 0.f, den = 0.f;
#pragma unroll 4
  for (int c = 0; c < NCHUNK; ++c) {
    num += part_num[((size_t)c * Mp + f) * Edim + e];
    den += part_den[(size_t)c * Mp + f];
  }
  ctx[idx] = num / den;
}

// out[b][e] = sum_f values[b][f] * ctx[f][e]
__global__ __launch_bounds__(256) void out_gemv_kernel(
    const float* __restrict__ values, const float* __restrict__ ctx,
    float* __restrict__ out) {
  const int b = blockIdx.x, tid = threadIdx.x;
  float acc[Edim];
#pragma unroll
  for (int e = 0; e < Edim; ++e) acc[e] = 0.f;
  for (int f = tid; f < Fdim; f += 256) {
    float v = values[b * Fdim + f];
    const float4* c4 = (const float4*)(ctx + f * Edim);
    float4 c0 = c4[0], c1 = c4[1], c2 = c4[2], c3 = c4[3];
    float cr[Edim] = {c0.x, c0.y, c0.z, c0.w, c1.x, c1.y, c1.z, c1.w,
                      c2.x, c2.y, c2.z, c2.w, c3.x, c3.y, c3.z, c3.w};
#pragma unroll
    for (int e = 0; e < Edim; ++e) acc[e] = fmaf(v, cr[e], acc[e]);
  }
  __shared__ float s_red[4][Edim];
  const int lane = tid & 63, wv = tid >> 6;
#pragma unroll
  for (int e = 0; e < Edim; ++e) {
    float a = wave64_sum(acc[e]);
    if (lane == 63) s_red[wv][e] = a;
  }
  __syncthreads();
  if (tid < Edim)
    out[b * Edim + tid] =
        s_red[0][tid] + s_red[1][tid] + s_red[2][tid] + s_red[3][tid];
}

extern "C" void kernel_launch(void* const* d_in, const int* in_sizes, int n_in,
                              void* d_out, int out_size, void* d_ws,
                              size_t ws_size, hipStream_t stream) {
  const float* values = (const float*)d_in[0];
  const float* femb   = (const float*)d_in[1];
  const float* hemb   = (const float*)d_in[2];
  const float* Ww     = (const float*)d_in[3];
  const float* bw     = (const float*)d_in[4];
  const float* Wu     = (const float*)d_in[5];
  const unsigned char* mask = (const unsigned char*)d_in[6];
  float* out = (float*)d_out;
  float* ws = (float*)d_ws;

  // ws layout (float units). Total ~14.5 MB.
  const size_t OFF_FLG = 0;                                   // 16
  const size_t OFF_A = 16;                                    // 128*10*512 f16 = 327680 f
  const size_t OFF_B = OFF_A + (size_t)128 * NKS * 256;       // 256*10*512 f16 = 655360 f
  const size_t OFF_HB = OFF_B + (size_t)256 * NKS * 256;      // 32768 f
  const size_t OFF_MB = OFF_HB + 32768;                       // Mp*NWRD u32 = 262144
  const size_t OFF_PN = OFF_MB + (size_t)Mp * NWRD;           // 2097152
  const size_t OFF_PD = OFF_PN + (size_t)NCHUNK * Mp * Edim;  // 131072
  const size_t OFF_CTX = OFF_PD + (size_t)NCHUNK * Mp;        // 32000

  int* mflag = (int*)(ws + OFF_FLG);
  _Float16* A2 = (_Float16*)(ws + OFF_A);
  _Float16* B2 = (_Float16*)(ws + OFF_B);
  _Float16* hembB = (_Float16*)(ws + OFF_HB);
  unsigned int* mbits = (unsigned int*)(ws + OFF_MB);
  float* part_num = ws + OFF_PN;
  float* part_den = ws + OFF_PD;
  float* ctx = ws + OFF_CTX;

  detect_mask_kernel<<<dim3(1), dim3(256), 0, stream>>>(mask, mflag);

  constexpr int PTOT = Fdim * Hdim + 3 * NKS * 256 + Wdim * Hdim +
                       6 * NKS * 256 + Mp * NWRD + (Np / 32) * 64;  // 677440
  prep2_kernel<<<dim3((PTOT + 255) / 256), dim3(256), 0, stream>>>(
      femb, hemb, Ww, bw, Wu, mask, mflag, A2, B2, mbits, hembB);

  score_ctx_kernel<<<dim3(32, 64), dim3(256), 0, stream>>>(
      A2, B2, mbits, hembB, part_num, part_den);

  finalize2_kernel<<<dim3((Fdim * Edim + 255) / 256), dim3(256), 0, stream>>>(
      part_num, part_den, ctx);

  out_gemv_kernel<<<dim3(Bdim), dim3(256), 0, stream>>>(values, ctx, out);
}